// Round 3
// baseline (114.946 us; speedup 1.0000x reference)
//
#include <hip/hip_runtime.h>
#include <hip/hip_bf16.h>

typedef __attribute__((ext_vector_type(8))) __bf16 bf16x8;
typedef __attribute__((ext_vector_type(4))) float f32x4;

#define DEVI static __device__ __forceinline__

DEVI unsigned short f2bf(float f) {
    union { float f; unsigned int u; } v; v.f = f;
    unsigned int u = v.u;
    u += 0x7FFFu + ((u >> 16) & 1u);   // RNE
    return (unsigned short)(u >> 16);
}

// ---------------------------------------------------------------------------
// prep: pack weights to bf16 in GEMM-friendly (column-major over output col)
// layouts.
//  WcatT[256][192]: col c<128 -> W_l row c, c>=128 -> W_r row c-128.
//  Packed K order is window order [x(n-1) | x(n) | x(n+1)].
//  xl feat order: [x(n) | x(n-1) | x(n+1)]  (shift_down first, then shift_up)
//    W_l: packed 0:64 <- feat 64:128, 64:128 <- feat 0:64, 128:192 <- feat 128:192
//  xr feat order: [x(n) | x(n+1) | x(n-1)]  (shift_up first, then shift_down)
//    W_r: packed 0:64 <- feat 128:192, 64:128 <- feat 0:64, 128:192 <- feat 64:128
//  WtT[256][128]: c = k*128+g, WtT[c][h] = W_bil[k][h][g]
// ---------------------------------------------------------------------------
__global__ void prep_kernel(const float* __restrict__ Wl,
                            const float* __restrict__ Wr,
                            const float* __restrict__ Wb,
                            unsigned short* __restrict__ WcatT,
                            unsigned short* __restrict__ WtT)
{
    int i = blockIdx.x * 256 + threadIdx.x;
    const int TOT = 256*192 + 256*128;
    if (i >= TOT) return;
    if (i < 256*192) {
        int c = i / 192, kk = i % 192;
        float v;
        if (c < 128) {
            int orig = (kk < 64) ? (kk + 64) : ((kk < 128) ? (kk - 64) : kk);
            v = Wl[c*192 + orig];
        } else {
            // round-2 bug: third block used orig=kk (x(n-1) weights) instead of
            // kk-64 (x(n+1) weights). Correct map: kk>=64 -> kk-64.
            int orig = (kk < 64) ? (kk + 128) : (kk - 64);
            v = Wr[(c-128)*192 + orig];
        }
        WcatT[i] = f2bf(v);
    } else {
        int j = i - 256*192;
        int c = j >> 7, h = j & 127;      // c: 0..255 output col, h: 0..127
        int k = c >> 7, g = c & 127;
        WtT[j] = f2bf(Wb[(k*128 + h)*128 + g]);
    }
}

// ---------------------------------------------------------------------------
// stage 1: per block: 32 rows (one batch slice).
//  1) x window rows n0-1..n0+32 -> LDS bf16
//  2) H = relu(Xwin @ WcatT^T + [b_l|b_r])  -> LDS Hbuf [32][256]
//  3) hr (cols 128:256) -> global bf16
//  4) T = hl @ WtT^T -> LDS Tbuf [32][256]  -> global bf16
// MFMA 16x16x32 bf16:  A[m=lane&15][k=q*8+j], B[k=q*8+j][n=lane&15],
//                      D[row=q*4+r][col=lane&15]
// ---------------------------------------------------------------------------
__global__ __launch_bounds__(256) void stage1_kernel(
    const float* __restrict__ x,
    const float* __restrict__ bl,
    const float* __restrict__ br,
    const unsigned short* __restrict__ WcatT,
    const unsigned short* __restrict__ WtT,
    unsigned short* __restrict__ t_out,   // [B*N][256], c = k*128+g
    unsigned short* __restrict__ hr_out)  // [B*N][128]
{
    __shared__ unsigned short xwin[34*72];   // rows padded 64->72 (16B-mult stride)
    __shared__ unsigned short Hbuf[32*264];  // 256 -> 264 pad
    __shared__ unsigned short Tbuf[32*264];

    const int tid = threadIdx.x;
    const int blk = blockIdx.x;           // 256 blocks, 32 per batch
    const int b   = blk >> 5;
    const int n0  = (blk & 31) << 5;

    // ---- 1) load x window rows n0-1 .. n0+32 (zero outside batch) ----
    for (int c = tid; c < 34*16; c += 256) {
        int row = c >> 4, ch = c & 15;
        int n = n0 - 1 + row;
        float4 v = make_float4(0.f, 0.f, 0.f, 0.f);
        if (n >= 0 && n < 1024)
            v = ((const float4*)(x + ((size_t)b*1024 + n)*64))[ch];
        unsigned short* d = &xwin[row*72 + ch*4];
        d[0]=f2bf(v.x); d[1]=f2bf(v.y); d[2]=f2bf(v.z); d[3]=f2bf(v.w);
    }
    __syncthreads();

    const int lane = tid & 63, wave = tid >> 6;
    const int q = lane >> 4, m = lane & 15;

    // ---- 2) H-GEMM: [32 x 192] @ [192 x 256] ----
    // packed feature kk multiplies x(n-1 + kk/64)[kk%64]; A row r -> n = n0+r,
    // so xwin row index = r + kk/64 (xwin row 0 is n0-1).
    bf16x8 a[2][6];
    #pragma unroll
    for (int rs = 0; rs < 2; ++rs)
        #pragma unroll
        for (int ks = 0; ks < 6; ++ks) {
            int row = rs*16 + m;
            int k = ks*32 + q*8;
            a[rs][ks] = *(const bf16x8*)&xwin[(row + (k >> 6))*72 + (k & 63)];
        }

    #pragma unroll
    for (int cs = 0; cs < 4; ++cs) {
        const int c0 = (wave*4 + cs)*16;
        bf16x8 bw[6];
        #pragma unroll
        for (int ks = 0; ks < 6; ++ks)
            bw[ks] = *(const bf16x8*)(WcatT + (size_t)(c0 + m)*192 + ks*32 + q*8);
        f32x4 acc0 = {0.f,0.f,0.f,0.f}, acc1 = {0.f,0.f,0.f,0.f};
        #pragma unroll
        for (int ks = 0; ks < 6; ++ks) {
            acc0 = __builtin_amdgcn_mfma_f32_16x16x32_bf16(a[0][ks], bw[ks], acc0, 0, 0, 0);
            acc1 = __builtin_amdgcn_mfma_f32_16x16x32_bf16(a[1][ks], bw[ks], acc1, 0, 0, 0);
        }
        const int c = c0 + m;                    // D col = lane&15
        const float bias = (c < 128) ? bl[c] : br[c - 128];
        #pragma unroll
        for (int r = 0; r < 4; ++r) {
            Hbuf[(q*4 + r)*264 + c]      = f2bf(fmaxf(acc0[r] + bias, 0.f));
            Hbuf[(16 + q*4 + r)*264 + c] = f2bf(fmaxf(acc1[r] + bias, 0.f));
        }
    }
    __syncthreads();

    // ---- 3) hr cooperative store: 32 rows x 128 bf16 = 512 chunks of 8 ----
    for (int c = tid; c < 512; c += 256) {
        int row = c >> 4, ch = c & 15;
        bf16x8 v = *(const bf16x8*)&Hbuf[row*264 + 128 + ch*8];
        *(bf16x8*)(hr_out + ((size_t)(b*1024 + n0 + row))*128 + ch*8) = v;
    }

    // ---- 4) T-GEMM: [32 x 128(hl)] @ [128 x 256] ----
    bf16x8 a2[2][4];
    #pragma unroll
    for (int rs = 0; rs < 2; ++rs)
        #pragma unroll
        for (int ks = 0; ks < 4; ++ks)
            a2[rs][ks] = *(const bf16x8*)&Hbuf[(rs*16 + m)*264 + ks*32 + q*8];

    #pragma unroll
    for (int cs = 0; cs < 4; ++cs) {
        const int c0 = (wave*4 + cs)*16;
        bf16x8 bw[4];
        #pragma unroll
        for (int ks = 0; ks < 4; ++ks)
            bw[ks] = *(const bf16x8*)(WtT + (size_t)(c0 + m)*128 + ks*32 + q*8);
        f32x4 acc0 = {0.f,0.f,0.f,0.f}, acc1 = {0.f,0.f,0.f,0.f};
        #pragma unroll
        for (int ks = 0; ks < 4; ++ks) {
            acc0 = __builtin_amdgcn_mfma_f32_16x16x32_bf16(a2[0][ks], bw[ks], acc0, 0, 0, 0);
            acc1 = __builtin_amdgcn_mfma_f32_16x16x32_bf16(a2[1][ks], bw[ks], acc1, 0, 0, 0);
        }
        const int c = c0 + m;
        #pragma unroll
        for (int r = 0; r < 4; ++r) {
            Tbuf[(q*4 + r)*264 + c]      = f2bf(acc0[r]);
            Tbuf[(16 + q*4 + r)*264 + c] = f2bf(acc1[r]);
        }
    }
    __syncthreads();

    // ---- T cooperative store: 32 rows x 256 bf16 = 1024 chunks of 8 ----
    for (int c = tid; c < 1024; c += 256) {
        int row = c >> 5, ch = c & 31;
        bf16x8 v = *(const bf16x8*)&Tbuf[row*264 + ch*8];
        *(bf16x8*)(t_out + ((size_t)(b*1024 + n0 + row))*256 + ch*8) = v;
    }
}

// ---------------------------------------------------------------------------
// stage 2: out[b,i,j,k] = sum_g t[b,i,k,g]*hr[b,j,g] + b_bil[k]
// grid (8 j-tiles, 16 i-tiles, 8 b). block 256 = 4 waves.
// block tile 64i x 128j; wave tile 32i x 64j x 2k. No LDS, direct L2 loads.
// ---------------------------------------------------------------------------
__global__ __launch_bounds__(256) void stage2_kernel(
    const unsigned short* __restrict__ t_in,   // [B*N][256]
    const unsigned short* __restrict__ hr_in,  // [B*N][128]
    const float* __restrict__ bbil,            // [2]
    float* __restrict__ out)                   // [B][N][N][2]
{
    const int b = blockIdx.z;
    const int tid = threadIdx.x, lane = tid & 63, wave = tid >> 6;
    const int q = lane >> 4, m = lane & 15;
    const int i0 = blockIdx.y*64 + (wave & 1)*32;
    const int j0 = blockIdx.x*128 + (wave >> 1)*64;

    const unsigned short* tb = t_in  + (size_t)b*1024*256;
    const unsigned short* hb = hr_in + (size_t)b*1024*128;

    f32x4 acc[2][2][4];
    #pragma unroll
    for (int ch = 0; ch < 2; ++ch)
        #pragma unroll
        for (int is = 0; is < 2; ++is)
            #pragma unroll
            for (int js = 0; js < 4; ++js)
                acc[ch][is][js] = (f32x4){0.f,0.f,0.f,0.f};

    #pragma unroll
    for (int ks = 0; ks < 4; ++ks) {
        bf16x8 af[2][2], bf[4];
        #pragma unroll
        for (int is = 0; is < 2; ++is) {
            const unsigned short* rp = tb + (size_t)(i0 + is*16 + m)*256 + ks*32 + q*8;
            af[0][is] = *(const bf16x8*)(rp);
            af[1][is] = *(const bf16x8*)(rp + 128);
        }
        #pragma unroll
        for (int js = 0; js < 4; ++js)
            bf[js] = *(const bf16x8*)(hb + (size_t)(j0 + js*16 + m)*128 + ks*32 + q*8);

        #pragma unroll
        for (int ch = 0; ch < 2; ++ch)
            #pragma unroll
            for (int is = 0; is < 2; ++is)
                #pragma unroll
                for (int js = 0; js < 4; ++js)
                    acc[ch][is][js] = __builtin_amdgcn_mfma_f32_16x16x32_bf16(
                        af[ch][is], bf[js], acc[ch][is][js], 0, 0, 0);
    }

    const float bb0 = bbil[0], bb1 = bbil[1];
    #pragma unroll
    for (int is = 0; is < 2; ++is)
        #pragma unroll
        for (int js = 0; js < 4; ++js)
            #pragma unroll
            for (int r = 0; r < 4; ++r) {
                int i = i0 + is*16 + q*4 + r;
                int j = j0 + js*16 + m;
                float2 v = make_float2(acc[0][is][js][r] + bb0,
                                       acc[1][is][js][r] + bb1);
                *(float2*)(out + ((size_t)(b*1024 + i)*1024 + j)*2) = v;
            }
}

extern "C" void kernel_launch(void* const* d_in, const int* in_sizes, int n_in,
                              void* d_out, int out_size, void* d_ws, size_t ws_size,
                              hipStream_t stream)
{
    const float* x    = (const float*)d_in[0];
    const float* Wl   = (const float*)d_in[1];
    const float* bl   = (const float*)d_in[2];
    const float* Wr   = (const float*)d_in[3];
    const float* br   = (const float*)d_in[4];
    const float* Wb   = (const float*)d_in[5];
    const float* bbil = (const float*)d_in[6];
    float* out = (float*)d_out;

    unsigned char* ws = (unsigned char*)d_ws;
    unsigned short* t_ws  = (unsigned short*)(ws);                      // 4 MiB
    unsigned short* hr_ws = (unsigned short*)(ws + (4u<<20));           // 2 MiB
    unsigned short* WcatT = (unsigned short*)(ws + (6u<<20));           // 96 KiB
    unsigned short* WtT   = (unsigned short*)(ws + (6u<<20) + 98304);   // 64 KiB

    prep_kernel<<<320, 256, 0, stream>>>(Wl, Wr, Wb, WcatT, WtT);
    stage1_kernel<<<256, 256, 0, stream>>>(x, bl, br, WcatT, WtT, t_ws, hr_ws);
    stage2_kernel<<<dim3(8, 16, 8), 256, 0, stream>>>(t_ws, hr_ws, bbil, out);
}